// Round 6
// baseline (699.966 us; speedup 1.0000x reference)
//
#include <hip/hip_runtime.h>
#include <hip/hip_bf16.h>
#include <math.h>

#define LQ   15000
#define LS_  15000
#define NB   2
#define ROWS (NB*LQ)   // 30000
#define HGT  100
#define WID  150

typedef __attribute__((ext_vector_type(8))) short bf16x8;
typedef __attribute__((ext_vector_type(4))) float f32x4;

enum { EP_BIAS_F32 = 0, EP_LN_BF = 1, EP_MASK_HM = 2, EP_RES_LN_BF = 3, EP_GELU_RES_LN_F32 = 4 };
enum { AM_BF16 = 0, AM_F32 = 1, AM_F32SUM = 2 };

__device__ inline short f2bf(float x) {
    __hip_bfloat16 h = __float2bfloat16(x);
    return *reinterpret_cast<short*>(&h);
}
__device__ inline unsigned pack2bf(float a, float b) {
    return ((unsigned)(unsigned short)f2bf(a)) | (((unsigned)(unsigned short)f2bf(b)) << 16);
}
__device__ inline float bf2f(short s) {
    return __uint_as_float(((unsigned)(unsigned short)s) << 16);
}
__device__ inline float gelu_exact(float x) {
    return 0.5f * x * (1.f + erff(x * 0.70710678118654752440f));
}

// ================================================================
// pgemm: persistent GEMM, whole W^T (BN x 256 bf16) resident in LDS.
// 256 blocks x 512 threads (8 waves). One barrier total. Each wave owns a
// 16-row tile: 8 A-fragment global loads, then 8*NT ds_read+MFMA with no
// barriers -> no convoy stalls. Epilogues fused (bias/LN/mask/gelu/residual).
// LDS = BN x 264 shorts (pad 264: row stride 528B = 4 banks -> 2-way, free).
// ================================================================
template<int NT, int EPI, int AMODE>
__global__ __launch_bounds__(512, 2) void pgemm(
    const void* __restrict__ Ap, const void* __restrict__ Ap2,
    const short* __restrict__ WT, const float* __restrict__ bias,
    void* __restrict__ Out, const void* __restrict__ Res,
    const unsigned char* __restrict__ mask,
    const float* __restrict__ lng, const float* __restrict__ lnb, int M)
{
    constexpr int BN = NT * 16;
    __shared__ short Bs[BN][264];

    const int tid  = threadIdx.x;
    const int wave = tid >> 6, lane = tid & 63;
    const int quad = lane >> 4, c = lane & 15;

    // ---- cooperative W load: BN*32 chunks of 16B ----
    #pragma unroll
    for (int id = tid; id < BN * 32; id += 512) {
        int n = id >> 5, kc = id & 31;
        *(int4*)&Bs[n][kc * 8] = *(const int4*)&WT[(size_t)n * 256 + kc * 8];
    }
    __syncthreads();

    const int ntiles = (M + 15) >> 4;
    for (int task = blockIdx.x * 8 + wave; task < ntiles; task += gridDim.x * 8) {
        const int r0 = task * 16;
        int ra = r0 + c; if (ra > M - 1) ra = M - 1;

        // ---- A fragments: 8 chunks of 16B (bf16) / 2x16B (f32) per lane ----
        bf16x8 a[8];
        if (AMODE == AM_BF16) {
            const short* A = (const short*)Ap;
            #pragma unroll
            for (int k = 0; k < 8; ++k)
                a[k] = *(const bf16x8*)&A[(size_t)ra * 256 + k * 32 + quad * 8];
        } else {
            const float* A  = (const float*)Ap;
            const float* A2 = (const float*)Ap2;
            #pragma unroll
            for (int k = 0; k < 8; ++k) {
                size_t base = (size_t)ra * 256 + k * 32 + quad * 8;
                float4 v0 = *(const float4*)&A[base];
                float4 v1 = *(const float4*)&A[base + 4];
                if (AMODE == AM_F32SUM) {
                    float4 w0 = *(const float4*)&A2[base];
                    float4 w1 = *(const float4*)&A2[base + 4];
                    v0.x += w0.x; v0.y += w0.y; v0.z += w0.z; v0.w += w0.w;
                    v1.x += w1.x; v1.y += w1.y; v1.z += w1.z; v1.w += w1.w;
                }
                int4 p;
                p.x = pack2bf(v0.x, v0.y); p.y = pack2bf(v0.z, v0.w);
                p.z = pack2bf(v1.x, v1.y); p.w = pack2bf(v1.z, v1.w);
                a[k] = *(bf16x8*)&p;
            }
        }

        f32x4 acc[NT];
        #pragma unroll
        for (int t = 0; t < NT; ++t) acc[t] = (f32x4){0.f, 0.f, 0.f, 0.f};

        #pragma unroll
        for (int k = 0; k < 8; ++k) {
            #pragma unroll
            for (int t = 0; t < NT; ++t) {
                bf16x8 b = *(const bf16x8*)&Bs[t * 16 + c][k * 32 + quad * 8];
                acc[t] = __builtin_amdgcn_mfma_f32_16x16x32_bf16(a[k], b, acc[t], 0, 0, 0);
            }
        }

        // ---- epilogue: lane owns rows r0+quad*4+reg, cols t*16+c ----
        if constexpr (EPI == EP_BIAS_F32) {
            float* O = (float*)Out;
            #pragma unroll
            for (int reg = 0; reg < 4; ++reg) {
                int r = r0 + quad * 4 + reg;
                if (r < M) {
                    #pragma unroll
                    for (int t = 0; t < NT; ++t) {
                        int col = t * 16 + c;
                        O[(size_t)r * BN + col] = acc[t][reg] + bias[col];
                    }
                }
            }
        } else if constexpr (EPI == EP_MASK_HM) {
            short* O = (short*)Out;
            #pragma unroll
            for (int reg = 0; reg < 4; ++reg) {
                int r = r0 + quad * 4 + reg;
                if (r < M) {
                    float mz = mask[r] ? 0.f : 1.f;
                    int n = (r >= LS_) ? 1 : 0;
                    int sidx = r - n * LS_;
                    #pragma unroll
                    for (int t = 0; t < NT; ++t) {
                        int col = t * 16 + c; int h = col >> 5, d = col & 31;
                        O[(((size_t)n * 8 + h) * LS_ + sidx) * 32 + d] =
                            f2bf((acc[t][reg] + bias[col]) * mz);
                    }
                }
            }
        } else {
            #pragma unroll
            for (int reg = 0; reg < 4; ++reg) {
                int r = r0 + quad * 4 + reg;
                int rl = (r < M) ? r : (M - 1);
                float s = 0.f, sq = 0.f;
                float vv[NT];
                #pragma unroll
                for (int t = 0; t < NT; ++t) {
                    int col = t * 16 + c;
                    float v = acc[t][reg] + bias[col];
                    if constexpr (EPI == EP_RES_LN_BF)
                        v += ((const float*)Res)[(size_t)rl * 256 + col];
                    else if constexpr (EPI == EP_GELU_RES_LN_F32)
                        v = gelu_exact(v) + bf2f(((const short*)Res)[(size_t)rl * 256 + col]);
                    vv[t] = v; s += v; sq += v * v;
                }
                #pragma unroll
                for (int o = 1; o < 16; o <<= 1) {
                    s += __shfl_xor(s, o, 64); sq += __shfl_xor(sq, o, 64);
                }
                float mean = s * (1.f / 256.f);
                float var  = sq * (1.f / 256.f) - mean * mean;
                float rs   = rsqrtf(var + 1e-5f);
                if (r < M) {
                    #pragma unroll
                    for (int t = 0; t < NT; ++t) {
                        int col = t * 16 + c;
                        float o = (vv[t] - mean) * rs * lng[col] + lnb[col];
                        if constexpr (EPI == EP_GELU_RES_LN_F32)
                            ((float*)Out)[(size_t)r * 256 + col] = o;
                        else
                            ((short*)Out)[(size_t)r * 256 + col] = f2bf(o);
                    }
                }
            }
        }
    }
}

// ================================================================
// deform_sample: 8 lanes per (r,h), 4 channels/lane; 7500 blocks for TLP.
// ================================================================
__global__ __launch_bounds__(256) void deform_sample(
    const short* __restrict__ value,   // [NB][8][LS_][32] bf16, head-major
    const float* __restrict__ S_oa,    // [ROWS, 96]
    const float* __restrict__ refp,    // [ROWS, 2]
    short* __restrict__ out)           // [ROWS, 256] bf16
{
    int grp = blockIdx.x * 32 + (threadIdx.x >> 3);
    int c4  = threadIdx.x & 7;
    int h = grp & 7;
    int r = grp >> 3;
    int n = (r >= LS_) ? 1 : 0;

    const float* row = S_oa + (size_t)r * 96;
    float rx = refp[(size_t)r * 2 + 0], ry = refp[(size_t)r * 2 + 1];
    float4 oA = *(const float4*)&row[h * 8];
    float4 oB = *(const float4*)&row[h * 8 + 4];
    float4 lg = *(const float4*)&row[64 + h * 4];

    float mx = fmaxf(fmaxf(lg.x, lg.y), fmaxf(lg.z, lg.w));
    float e0 = expf(lg.x - mx), e1 = expf(lg.y - mx), e2 = expf(lg.z - mx), e3 = expf(lg.w - mx);
    float inv = 1.f / (e0 + e1 + e2 + e3);
    float aw[4] = {e0 * inv, e1 * inv, e2 * inv, e3 * inv};
    float ox[4] = {oA.x, oA.z, oB.x, oB.z};
    float oy[4] = {oA.y, oA.w, oB.y, oB.w};

    const short* vb = value + (((size_t)n * 8 + h) * LS_) * 32 + c4 * 4;
    float a0 = 0.f, a1 = 0.f, a2 = 0.f, a3 = 0.f;

    #pragma unroll
    for (int p = 0; p < 4; ++p) {
        float x = rx * (float)WID + ox[p] - 0.5f;
        float y = ry * (float)HGT + oy[p] - 0.5f;
        float x0f = floorf(x), y0f = floorf(y);
        float lx = x - x0f, ly = y - y0f;
        int x0 = (int)x0f, y0 = (int)y0f;
        int x1 = x0 + 1, y1 = y0 + 1;
        bool vx0 = (x0 >= 0) & (x0 < WID), vx1 = (x1 >= 0) & (x1 < WID);
        bool vy0 = (y0 >= 0) & (y0 < HGT), vy1 = (y1 >= 0) & (y1 < HGT);
        float w00 = (vx0 & vy0) ? (1.f - lx) * (1.f - ly) * aw[p] : 0.f;
        float w10 = (vx1 & vy0) ? lx * (1.f - ly) * aw[p] : 0.f;
        float w01 = (vx0 & vy1) ? (1.f - lx) * ly * aw[p] : 0.f;
        float w11 = (vx1 & vy1) ? lx * ly * aw[p] : 0.f;
        int xc0 = min(max(x0, 0), WID - 1), xc1 = min(max(x1, 0), WID - 1);
        int yc0 = min(max(y0, 0), HGT - 1), yc1 = min(max(y1, 0), HGT - 1);
        int2 v00 = *(const int2*)&vb[(size_t)(yc0 * WID + xc0) * 32];
        int2 v10 = *(const int2*)&vb[(size_t)(yc0 * WID + xc1) * 32];
        int2 v01 = *(const int2*)&vb[(size_t)(yc1 * WID + xc0) * 32];
        int2 v11 = *(const int2*)&vb[(size_t)(yc1 * WID + xc1) * 32];
        a0 += w00 * __uint_as_float(((unsigned)v00.x) << 16)
            + w10 * __uint_as_float(((unsigned)v10.x) << 16)
            + w01 * __uint_as_float(((unsigned)v01.x) << 16)
            + w11 * __uint_as_float(((unsigned)v11.x) << 16);
        a1 += w00 * __uint_as_float(v00.x & 0xffff0000u)
            + w10 * __uint_as_float(v10.x & 0xffff0000u)
            + w01 * __uint_as_float(v01.x & 0xffff0000u)
            + w11 * __uint_as_float(v11.x & 0xffff0000u);
        a2 += w00 * __uint_as_float(((unsigned)v00.y) << 16)
            + w10 * __uint_as_float(((unsigned)v10.y) << 16)
            + w01 * __uint_as_float(((unsigned)v01.y) << 16)
            + w11 * __uint_as_float(((unsigned)v11.y) << 16);
        a3 += w00 * __uint_as_float(v00.y & 0xffff0000u)
            + w10 * __uint_as_float(v10.y & 0xffff0000u)
            + w01 * __uint_as_float(v01.y & 0xffff0000u)
            + w11 * __uint_as_float(v11.y & 0xffff0000u);
    }
    int2 o;
    o.x = pack2bf(a0, a1);
    o.y = pack2bf(a2, a3);
    *(int2*)&out[(size_t)r * 256 + h * 32 + c4 * 4] = o;
}

// ================================================================
// prep_all: all weight prep in one dispatch (401 blocks)
// ================================================================
__global__ __launch_bounds__(256) void prep_all(
    const float* __restrict__ W_dsa, const float* __restrict__ W_val,
    const float* __restrict__ W_ff,  const float* __restrict__ W_out,
    const float* __restrict__ W_csa, const float* __restrict__ b_out,
    const float* __restrict__ b_csa, const float* __restrict__ W_off,
    const float* __restrict__ W_attn, const float* __restrict__ b_off,
    const float* __restrict__ b_attn,
    short* __restrict__ WT_dsa, short* __restrict__ WT_val, short* __restrict__ WT_ff,
    short* __restrict__ WT_c, float* __restrict__ bc,
    short* __restrict__ WT_oa, float* __restrict__ b_oa)
{
    __shared__ float tile[64][65];
    const int b = blockIdx.x, tid = threadIdx.x;
    if (b < 48) {
        const float* W = (b < 16) ? W_dsa : (b < 32) ? W_val : W_ff;
        short* WT = (b < 16) ? WT_dsa : (b < 32) ? WT_val : WT_ff;
        int t = b & 15; int bx = (t & 3) * 64, by = (t >> 2) * 64;
        #pragma unroll
        for (int it = 0; it < 4; ++it) {
            int f = it * 256 + tid; int i = f >> 4; int j = (f & 15) * 4;
            float4 v = *(const float4*)&W[(size_t)(by + i) * 256 + bx + j];
            tile[i][j] = v.x; tile[i][j + 1] = v.y; tile[i][j + 2] = v.z; tile[i][j + 3] = v.w;
        }
        __syncthreads();
        #pragma unroll
        for (int it = 0; it < 16; ++it) {
            int f = it * 256 + tid; int nl = f >> 6; int kl = f & 63;
            WT[(size_t)(bx + nl) * 256 + by + kl] = f2bf(tile[kl][nl]);
        }
    } else if (b < 304) {
        int k = b - 48, n = tid;
        float s = 0.f;
        #pragma unroll 8
        for (int j = 0; j < 256; ++j)
            s = fmaf(W_out[(size_t)k * 256 + j], W_csa[(size_t)j * 256 + n], s);
        WT_c[(size_t)n * 256 + k] = f2bf(s);
    } else if (b == 304) {
        int j = tid;
        float s = b_csa[j];
        #pragma unroll 8
        for (int k = 0; k < 256; ++k)
            s = fmaf(b_out[k], W_csa[(size_t)k * 256 + j], s);
        bc[j] = s;
    } else {
        int j = b - 305, k = tid;
        float v = (j < 64) ? W_off[(size_t)k * 64 + j] : W_attn[(size_t)k * 32 + (j - 64)];
        WT_oa[(size_t)j * 256 + k] = f2bf(v);
        if (k == 0) b_oa[j] = (j < 64) ? b_off[j] : b_attn[j - 64];
    }
}

// ================= launcher =================
extern "C" void kernel_launch(void* const* d_in, const int* in_sizes, int n_in,
                              void* d_out, int out_size, void* d_ws, size_t ws_size,
                              hipStream_t stream)
{
    const float* tgt       = (const float*)d_in[0];
    const float* query_pos = (const float*)d_in[1];
    const float* refp      = (const float*)d_in[4];
    const float* src       = (const float*)d_in[6];
    const unsigned char* mask = (const unsigned char*)d_in[9];
    const float* W_dsa  = (const float*)d_in[10]; const float* b_dsa  = (const float*)d_in[11];
    const float* g_nds  = (const float*)d_in[12]; const float* b_nds  = (const float*)d_in[13];
    const float* W_off  = (const float*)d_in[14]; const float* b_off  = (const float*)d_in[15];
    const float* W_attn = (const float*)d_in[16]; const float* b_attn = (const float*)d_in[17];
    const float* W_val  = (const float*)d_in[18]; const float* b_val  = (const float*)d_in[19];
    const float* W_out  = (const float*)d_in[20]; const float* b_out  = (const float*)d_in[21];
    const float* W_csa  = (const float*)d_in[22]; const float* b_csa  = (const float*)d_in[23];
    const float* g_n1   = (const float*)d_in[24]; const float* b_n1   = (const float*)d_in[25];
    const float* W_ff   = (const float*)d_in[26]; const float* b_ff   = (const float*)d_in[27];
    const float* g_n3   = (const float*)d_in[28]; const float* b_n3   = (const float*)d_in[29];
    float* out = (float*)d_out;

    short* buf0     = (short*)d_ws;                          // src_a / t        [ROWS*256] bf16
    short* attn_out = buf0 + (size_t)ROWS * 256;             // attn_out         [ROWS*256] bf16
    short* value    = attn_out + (size_t)ROWS * 256;         // value head-major [ROWS*256] bf16
    float* S_oa     = (float*)(value + (size_t)ROWS * 256);  // [ROWS*96] f32
    short* WT_dsa   = (short*)(S_oa + (size_t)ROWS * 96);
    short* WT_val   = WT_dsa + 65536;
    short* WT_ff    = WT_val + 65536;
    short* WT_c     = WT_ff + 65536;
    short* WT_oa    = WT_c + 65536;                          // 96*256
    float* bc       = (float*)(WT_oa + 96 * 256);
    float* b_oa     = bc + 256;

    prep_all<<<401, dim3(256), 0, stream>>>(
        W_dsa, W_val, W_ff, W_out, W_csa, b_out, b_csa, W_off, W_attn, b_off, b_attn,
        WT_dsa, WT_val, WT_ff, WT_c, bc, WT_oa, b_oa);

    dim3 pb(512);

    // S_oa = (tgt+qpos)@[W_off|W_attn]+b   (independent of value path)
    pgemm<6, EP_BIAS_F32, AM_F32SUM><<<256, pb, 0, stream>>>(
        tgt, query_pos, WT_oa, b_oa, S_oa, nullptr, nullptr, nullptr, nullptr, ROWS);

    // src_a = LN(src@W_dsa+b_dsa)  -> bf16
    pgemm<16, EP_LN_BF, AM_F32><<<256, pb, 0, stream>>>(
        src, nullptr, WT_dsa, b_dsa, buf0, nullptr, nullptr, g_nds, b_nds, ROWS);

    // value = mask(src_a@W_val+b_val), head-major
    pgemm<16, EP_MASK_HM, AM_BF16><<<256, pb, 0, stream>>>(
        buf0, nullptr, WT_val, b_val, value, nullptr, mask, nullptr, nullptr, ROWS);

    // attn_out = deform-sample (softmax fused)
    deform_sample<<<ROWS * 8 / 32, dim3(256), 0, stream>>>(value, S_oa, refp, attn_out);

    // t = LN(tgt + attn_out@Wc+bc)  -> bf16   (Wc = W_out@W_csa collapsed)
    pgemm<16, EP_RES_LN_BF, AM_BF16><<<256, pb, 0, stream>>>(
        attn_out, nullptr, WT_c, bc, buf0, tgt, nullptr, g_n1, b_n1, ROWS);

    // out = LN(t + gelu(t@W_ff+b_ff))  -> f32
    pgemm<16, EP_GELU_RES_LN_F32, AM_BF16><<<256, pb, 0, stream>>>(
        buf0, nullptr, WT_ff, b_ff, out, buf0, nullptr, g_n3, b_n3, ROWS);
}